// Round 17
// baseline (402.909 us; speedup 1.0000x reference)
//
#include <hip/hip_runtime.h>
#include <cstdint>

#define HD 128
#define ED 32
#define BME 32            // edges per tile (edge kernel)
#define BMN 128           // nodes per block (node kernel)
#define PAD_N 264         // node sA row stride f16: 256+8
#define PAD_T 136         // node sT row stride f16: 128+8
#define EGRID 768         // persistent edge blocks (3 per CU @ 45KB LDS)

typedef _Float16 f16;
typedef __attribute__((ext_vector_type(2))) _Float16 f16x2;
typedef __attribute__((ext_vector_type(4))) _Float16 f16x4;
typedef __attribute__((ext_vector_type(8))) _Float16 f16x8;
typedef __attribute__((ext_vector_type(4))) float    f32x4;

__device__ __forceinline__ f32x4 mfma16(f16x8 a, f16x8 b, f32x4 c) {
    return __builtin_amdgcn_mfma_f32_16x16x32_f16(a, b, c, 0, 0, 0);
}
__device__ __forceinline__ f16x8 cvt8(const float* p) {
    const float4 a0 = *(const float4*)p;
    const float4 a1 = *(const float4*)(p + 4);
    f16x8 v;
    v[0] = (f16)a0.x; v[1] = (f16)a0.y; v[2] = (f16)a0.z; v[3] = (f16)a0.w;
    v[4] = (f16)a1.x; v[5] = (f16)a1.y; v[6] = (f16)a1.z; v[7] = (f16)a1.w;
    return v;
}
// barrier that drains LDS only — vmem loads/stores stay in flight (T4)
__device__ __forceinline__ void barrier_lds() {
    asm volatile("s_waitcnt lgkmcnt(0)" ::: "memory");
    __builtin_amdgcn_s_barrier();
    __builtin_amdgcn_sched_barrier(0);
}

// ---------------------------------------------------------------- utility
__global__ __launch_bounds__(256) void zero_f32(float4* p, long n4) {
    long i = (long)blockIdx.x * blockDim.x + threadIdx.x;
    const long stride = (long)gridDim.x * blockDim.x;
    const float4 z = make_float4(0.f, 0.f, 0.f, 0.f);
    for (; i < n4; i += stride) p[i] = z;
}
__global__ __launch_bounds__(256) void zero_i32(int* p, int n) {
    int i = blockIdx.x * blockDim.x + threadIdx.x;
    if (i < n) p[i] = 0;
}
__global__ __launch_bounds__(256)
void cvt_f16_kernel(const float* __restrict__ x, f16* __restrict__ y, long n8) {
    long i = blockIdx.x * 256 + threadIdx.x;
    const long stride = (long)gridDim.x * 256;
    for (; i < n8; i += stride) *(f16x8*)(y + i * 8) = cvt8(x + i * 8);
}
// pack all 4 weight mats -> frag order [kt][wi][lane][8] f16  (wi = hid16 slice)
__global__ __launch_bounds__(256)
void pack_all_kernel(const float* __restrict__ ew1, const float* __restrict__ ew2,
                     const float* __restrict__ nw1, const float* __restrict__ nw2,
                     f16* __restrict__ w1p, f16* __restrict__ w2p,
                     f16* __restrict__ n1p, f16* __restrict__ n2p)
{
    const int b = blockIdx.x;
    const float* w; f16* wp; int base;
    if (b < 18)      { w = ew1; wp = w1p; base = b; }
    else if (b < 26) { w = ew2; wp = w2p; base = b - 18; }
    else if (b < 42) { w = nw1; wp = n1p; base = b - 26; }
    else             { w = nw2; wp = n2p; base = b - 42; }
    const int idx = base * 256 + threadIdx.x;
    const int l  = idx & 63;
    const int fr = idx >> 6;
    const int wi = fr & 7, kt = fr >> 3;
    const int lii = l & 15, qq = l >> 4;
    const float* p = w + (size_t)(32 * kt + 8 * qq) * HD + 16 * wi + lii;
    f16x8 v;
#pragma unroll
    for (int e2 = 0; e2 < 8; ++e2) v[e2] = (f16)p[(size_t)e2 * HD];
    *(f16x8*)(wp + (size_t)idx * 8) = v;
}

// ---------------------------------------------------------------- CSR build
__global__ __launch_bounds__(256)
void hist_kernel(const int* __restrict__ eidx, int* __restrict__ rank,
                 int* __restrict__ cnt, int E) {
    int e = blockIdx.x * 256 + threadIdx.x;
    if (e < E) rank[e] = atomicAdd(&cnt[eidx[E + e]], 1);
}
// 3-phase parallel exclusive scan: 1024 elements per block
__global__ __launch_bounds__(256)
void scan1_kernel(const int* __restrict__ cnt, int* __restrict__ bsum, int N) {
    const int b = blockIdx.x, t = threadIdx.x;
    const int base = b * 1024 + t * 4;
    int s = 0;
#pragma unroll
    for (int j = 0; j < 4; ++j) { int i = base + j; s += (i < N) ? cnt[i] : 0; }
#pragma unroll
    for (int off = 1; off < 64; off <<= 1) s += __shfl_xor(s, off, 64);
    __shared__ int ws[4];
    if ((t & 63) == 0) ws[t >> 6] = s;
    __syncthreads();
    if (t == 0) bsum[b] = ws[0] + ws[1] + ws[2] + ws[3];
}
__global__ __launch_bounds__(256)
void scan2_kernel(const int* __restrict__ bsum, int* __restrict__ boff,
                  int* __restrict__ rs, int nb, int N) {
    const int t = threadIdx.x, lane = t & 63, w = t >> 6;
    int v = (t < nb) ? bsum[t] : 0;
    int incl = v;
#pragma unroll
    for (int off = 1; off < 64; off <<= 1) {
        int u = __shfl_up(incl, off, 64);
        if (lane >= off) incl += u;
    }
    __shared__ int ws[4];
    if (lane == 63) ws[w] = incl;
    __syncthreads();
    int wo = 0;
    for (int k = 0; k < w; ++k) wo += ws[k];
    const int excl = wo + incl - v;
    if (t < nb) boff[t] = excl;
    if (t == nb - 1) rs[N] = excl + v;
}
__global__ __launch_bounds__(256)
void scan3_kernel(const int* __restrict__ cnt, const int* __restrict__ boff,
                  int* __restrict__ rs, int N) {
    const int b = blockIdx.x, t = threadIdx.x;
    const int base = b * 1024 + t * 4;
    int v[4]; int ts = 0;
#pragma unroll
    for (int j = 0; j < 4; ++j) { int i = base + j; v[j] = (i < N) ? cnt[i] : 0; ts += v[j]; }
    const int lane = t & 63, w = t >> 6;
    int incl = ts;
#pragma unroll
    for (int off = 1; off < 64; off <<= 1) {
        int u = __shfl_up(incl, off, 64);
        if (lane >= off) incl += u;
    }
    __shared__ int ws[4];
    if (lane == 63) ws[w] = incl;
    __syncthreads();
    int wo = 0;
    for (int k = 0; k < w; ++k) wo += ws[k];
    int run = boff[b] + wo + incl - ts;
#pragma unroll
    for (int j = 0; j < 4; ++j) {
        int i = base + j;
        if (i < N) rs[i] = run;
        run += v[j];
    }
}
// scatter sorted index arrays: slot -> (src, dst, edge)
__global__ __launch_bounds__(256)
void pos_kernel(const int* __restrict__ eidx, const int* __restrict__ rs,
                const int* __restrict__ rank,
                int* __restrict__ esrc, int* __restrict__ edst,
                int* __restrict__ eea, int E) {
    int e = blockIdx.x * 256 + threadIdx.x;
    if (e < E) {
        const int dst = eidx[E + e];
        const int p = rs[dst] + rank[e];
        esrc[p] = eidx[e];
        edst[p] = dst;
        eea[p]  = e;
    }
}

// ---------------------------------------------------------------- edges
// CSR-slot order; fused per-tile dst-reduction: private dsts -> agg direct,
// boundary dsts (touch slot 0 / last) -> bnd partials. No atomics (MODE1).
// MODE 0: fp32 atomic scatter into agg (fallback).
template <int MODE>
__global__ __launch_bounds__(256, 2)
void edge_kernel(const f16*   __restrict__ h16,
                 const int*   __restrict__ eidx,
                 const float* __restrict__ ea,
                 const f16*   __restrict__ w1p,   // packed frags, KT=9
                 const float* __restrict__ b1,
                 const f16*   __restrict__ w2p,   // packed frags, KT=4
                 const float* __restrict__ b2,
                 float*       __restrict__ agg,   // [N][HD] f32
                 float*       __restrict__ bnd,   // [2*ntiles][HD] f32 (MODE1)
                 int*         __restrict__ bndid, // [2*ntiles] (MODE1)
                 const int*   __restrict__ esrc,  // MODE1 sorted indices
                 const int*   __restrict__ edst,
                 const int*   __restrict__ eea,
                 int E, int ntiles)
{
    __shared__ __align__(16) f16   sA  [BME * 320];  // 20480 B
    __shared__ __align__(16) f16   sT  [BME * 128];  // 8192 B
    __shared__ __align__(16) float sToF[BME * 128];  // 16384 B (m2 tile, f32)
    __shared__ int sIdx[2][BME];                     // dst per slot

    const int t  = threadIdx.x;
    const int l  = t & 63;
    const int wv = t >> 6;            // 0..3  (hid slice [32wv, 32wv+32))
    const int li = l & 15;
    const int q  = l >> 4;            // 0..3
    const int lm = l & 7;             // row&7
    const int r  = t >> 3;            // staging row 0..31
    const int q8 = t & 7;             // staging chunk id within row

    // ---- weights -> registers, once per block (104 VGPR, resident) ----
    f16x8 A1[2][9], A2[2][4];
#pragma unroll
    for (int ht = 0; ht < 2; ++ht) {
#pragma unroll
        for (int kt = 0; kt < 9; ++kt)
            A1[ht][kt] = *(const f16x8*)(w1p + ((size_t)(kt * 8 + wv * 2 + ht) * 64 + l) * 8);
#pragma unroll
        for (int kt = 0; kt < 4; ++kt)
            A2[ht][kt] = *(const f16x8*)(w2p + ((size_t)(kt * 8 + wv * 2 + ht) * 64 + l) * 8);
    }

    // ---- prefetch: tile row-data -> registers (flat indices) ----
    f16x8 d[4];
    f16x8 d4;                          // ea chunk (q8<4 only)
    int   psr = 0;
    auto prefetch = [&](int tile) {
        const int slot = min(tile * BME + r, E - 1);
        int src, dst, e;
        if (MODE == 0) {
            e = slot; src = eidx[e]; dst = eidx[E + e];
        } else {
            src = esrc[slot]; dst = edst[slot]; e = eea[slot];
        }
        psr = dst;
        const f16* hs = h16 + (size_t)src * HD;
        const f16* hd = h16 + (size_t)dst * HD;
#pragma unroll
        for (int i = 0; i < 4; ++i) {
            const int c = (q8 + 8 * i) * 8;        // < 256 always
            d[i] = (c < HD) ? *(const f16x8*)(hs + c)
                            : *(const f16x8*)(hd + (c - HD));
        }
        if (q8 < 4) d4 = cvt8(ea + (size_t)e * ED + q8 * 8);
    };

    int tb = blockIdx.x;
    if (tb < ntiles) prefetch(tb);
    int par = 0;

    for (; tb < ntiles; tb += gridDim.x, par ^= 1) {
        // ---- stage regs -> sA (swizzled) ----
        {
            f16* row = sA + r * 320;
            const int sw = r & 7;
#pragma unroll
            for (int i = 0; i < 4; ++i) {
                const int ch = q8 + 8 * i;
                *(f16x8*)(row + ((ch ^ sw) * 8)) = d[i];
            }
            if (q8 < 4)
                *(f16x8*)(row + (((q8 + 32) ^ sw) * 8)) = d4;
            if (q8 == 0) sIdx[par][r] = psr;
        }
        barrier_lds();                                    // S1: sA ready

        const int nt = tb + (int)gridDim.x;
        if (nt < ntiles) prefetch(nt);                    // floats across barriers

        // ---- GEMM1: K=288; 1 ds_read feeds 2 MFMAs ----
        f32x4 acc[2][2];
#pragma unroll
        for (int i = 0; i < 2; ++i)
#pragma unroll
            for (int j = 0; j < 2; ++j) acc[i][j] = (f32x4){0.f, 0.f, 0.f, 0.f};
#pragma unroll
        for (int kt = 0; kt < 9; ++kt) {
#pragma unroll
            for (int e = 0; e < 2; ++e) {
                const f16x8 b = *(const f16x8*)(sA + (16 * e + li) * 320
                                                + (((4 * kt + q) ^ lm) * 8));
                acc[0][e] = mfma16(A1[0][kt], b, acc[0][e]);
                acc[1][e] = mfma16(A1[1][kt], b, acc[1][e]);
            }
        }

        // ---- epilogue1: +b1, relu -> sT (swizzled) ----
#pragma unroll
        for (int ht = 0; ht < 2; ++ht) {
            const int hidb = 32 * wv + 16 * ht + 4 * q;
            const float4 bb = *(const float4*)(b1 + hidb);
            const int chT = hidb >> 3;
            const int off = hidb & 7;                     // 0 or 4
#pragma unroll
            for (int e = 0; e < 2; ++e) {
                const f32x4 v = acc[ht][e];
                float x0 = fmaxf(v[0] + bb.x, 0.f), x1 = fmaxf(v[1] + bb.y, 0.f);
                float x2 = fmaxf(v[2] + bb.z, 0.f), x3 = fmaxf(v[3] + bb.w, 0.f);
                f16x4 o; o[0] = (f16)x0; o[1] = (f16)x1; o[2] = (f16)x2; o[3] = (f16)x3;
                *(f16x4*)(sT + (16 * e + li) * 128 + ((chT ^ lm) * 8) + off) = o;
            }
        }
        barrier_lds();                                    // S2: sT ready

        // ---- GEMM2: K=128 ----
        f32x4 acc2[2][2];
#pragma unroll
        for (int i = 0; i < 2; ++i)
#pragma unroll
            for (int j = 0; j < 2; ++j) acc2[i][j] = (f32x4){0.f, 0.f, 0.f, 0.f};
#pragma unroll
        for (int kt = 0; kt < 4; ++kt) {
#pragma unroll
            for (int e = 0; e < 2; ++e) {
                const f16x8 b = *(const f16x8*)(sT + (16 * e + li) * 128
                                                + (((4 * kt + q) ^ lm) * 8));
                acc2[0][e] = mfma16(A2[0][kt], b, acc2[0][e]);
                acc2[1][e] = mfma16(A2[1][kt], b, acc2[1][e]);
            }
        }

        if (MODE == 0) {
#pragma unroll
            for (int ht = 0; ht < 2; ++ht) {
                const int hidb = 32 * wv + 16 * ht + 4 * q;
                const float4 bb = *(const float4*)(b2 + hidb);
#pragma unroll
                for (int e = 0; e < 2; ++e) {
                    const int edge = 16 * e + li;
                    if (tb * BME + edge < E) {
                        float* p = agg + (size_t)sIdx[par][edge] * HD + hidb;
                        const f32x4 v = acc2[ht][e];
                        atomicAdd(p + 0, v[0] + bb.x);
                        atomicAdd(p + 1, v[1] + bb.y);
                        atomicAdd(p + 2, v[2] + bb.z);
                        atomicAdd(p + 3, v[3] + bb.w);
                    }
                }
            }
            barrier_lds();
        } else {
            // ---- epilogue2: +b2 -> sToF (f32, swizzled per 16B quad) ----
#pragma unroll
            for (int ht = 0; ht < 2; ++ht) {
                const int hidb = 32 * wv + 16 * ht + 4 * q;
                const float4 bb = *(const float4*)(b2 + hidb);
                const int ch = hidb >> 2;                 // f32-quad 0..31
#pragma unroll
                for (int e = 0; e < 2; ++e) {
                    const int row = 16 * e + li;
                    const f32x4 v = acc2[ht][e];
                    f32x4 x;
                    x[0] = v[0] + bb.x; x[1] = v[1] + bb.y;
                    x[2] = v[2] + bb.z; x[3] = v[3] + bb.w;
                    *(f32x4*)(sToF + row * 128 + ((ch ^ ((row & 7) << 2)) << 2)) = x;
                }
            }
            barrier_lds();                                // S3: m2 tile ready

            // ---- tile-local dst reduction: 128 threads, one column each ----
            if (t < 128) {
                const int col  = t;
                const int ch   = col >> 2;
                const int co   = col & 3;
                const int sLast = min(BME - 1, E - 1 - tb * BME);
                float run = 0.f;
                int   rdst = sIdx[par][0];
                bool  touches0 = true;
                for (int s = 0; s <= sLast; ++s) {
                    const int ds = sIdx[par][s];
                    if (ds != rdst) {
                        if (touches0) {
                            bnd[((size_t)2 * tb) * HD + col] = run;
                            if (col == 0) bndid[2 * tb] = rdst;
                        } else {
                            agg[(size_t)rdst * HD + col] = run;   // private dst
                        }
                        run = 0.f; rdst = ds; touches0 = false;
                    }
                    run += sToF[s * 128 + ((ch ^ ((s & 7) << 2)) << 2) + co];
                }
                if (touches0) {  // single run spans whole tile
                    bnd[((size_t)2 * tb) * HD + col]     = run;
                    bnd[((size_t)2 * tb + 1) * HD + col] = 0.f;
                    if (col == 0) { bndid[2 * tb] = rdst; bndid[2 * tb + 1] = rdst; }
                } else {
                    bnd[((size_t)2 * tb + 1) * HD + col] = run;
                    if (col == 0) bndid[2 * tb + 1] = rdst;
                }
            }
        }
    }
}

// ---------------------------------------------------------------- fixup
// boundary entries for one dst are consecutive; run-start wave sums & stores.
__global__ __launch_bounds__(256)
void fixup_kernel(const float* __restrict__ bnd, const int* __restrict__ bndid,
                  float* __restrict__ agg, int nent)
{
    const int lane = threadIdx.x & 63;
    int i = blockIdx.x * 4 + (threadIdx.x >> 6);
    const int stride = gridDim.x * 4;
    for (; i < nent; i += stride) {
        const int d = bndid[i];
        if (i > 0 && bndid[i - 1] == d) continue;       // not a run start
        float s0 = bnd[(size_t)i * HD + lane];
        float s1 = bnd[(size_t)i * HD + 64 + lane];
        int j = i + 1;
        while (j < nent && bndid[j] == d) {
            s0 += bnd[(size_t)j * HD + lane];
            s1 += bnd[(size_t)j * HD + 64 + lane];
            ++j;
        }
        agg[(size_t)d * HD + lane]      = s0;
        agg[(size_t)d * HD + 64 + lane] = s1;
    }
}

// ---------------------------------------------------------------- nodes
// agg read as dense f32 (aggf); h16 for features; h f32 residual.
__global__ __launch_bounds__(256, 2)
void node_kernel(const f16*   __restrict__ h16,
                 const float* __restrict__ h,      // f32 residual
                 const float* __restrict__ aggf,
                 const f16*   __restrict__ w1p,    // KT=8
                 const float* __restrict__ b1,
                 const f16*   __restrict__ w2p,    // KT=4
                 const float* __restrict__ b2,
                 const float* __restrict__ gamma,
                 const float* __restrict__ beta,
                 float*       __restrict__ out,
                 int N)
{
    __shared__ __align__(16) f16 sA[BMN * PAD_N];  // 67584 B; sT & sX alias
    __shared__ float sMV[2 * BMN];

    const int t  = threadIdx.x;
    const int l  = t & 63;
    const int wv = t >> 6;
    const int li = l & 15;
    const int q  = l >> 4;
    const int nbase = blockIdx.x * BMN;

    // ---- stage sA[node][0..256) = [h16 | cvt(aggf)] : 2 threads/node ----
    {
        const int r = t >> 1, half = t & 1;
        const int node = min(nbase + r, N - 1);
        f16* rowp = sA + r * PAD_N;
        {
            const f16* srcp = h16 + (size_t)node * HD + half * 64;
#pragma unroll
            for (int i = 0; i < 8; ++i)
                *(f16x8*)(rowp + half * 64 + i * 8) = *(const f16x8*)(srcp + i * 8);
        }
        {
            const float* srcp = aggf + (size_t)node * HD + half * 64;
#pragma unroll
            for (int i = 0; i < 8; ++i)
                *(f16x8*)(rowp + 128 + half * 64 + i * 8) = cvt8(srcp + i * 8);
        }
    }
    __syncthreads();                                  // S1

    // ---- A1 -> registers ----
    f16x8 A1[2][8];
#pragma unroll
    for (int ht = 0; ht < 2; ++ht)
#pragma unroll
        for (int kt = 0; kt < 8; ++kt)
            A1[ht][kt] = *(const f16x8*)(w1p + ((size_t)(kt * 8 + wv * 2 + ht) * 64 + l) * 8);

    // ---- GEMM1: K=256 ----
    f32x4 acc[2][8];
#pragma unroll
    for (int i = 0; i < 2; ++i)
#pragma unroll
        for (int j = 0; j < 8; ++j) acc[i][j] = (f32x4){0.f, 0.f, 0.f, 0.f};
#pragma unroll
    for (int kt = 0; kt < 8; ++kt) {
#pragma unroll
        for (int et = 0; et < 8; ++et) {
            const f16x8 b = *(const f16x8*)(sA + (16 * et + li) * PAD_N + 32 * kt + 8 * q);
            acc[0][et] = mfma16(A1[0][kt], b, acc[0][et]);
            acc[1][et] = mfma16(A1[1][kt], b, acc[1][et]);
        }
    }
    __syncthreads();                                  // S2: sA reads done (alias!)

    // ---- A2 -> registers ----
    f16x8 A2[2][4];
#pragma unroll
    for (int ht = 0; ht < 2; ++ht)
#pragma unroll
        for (int kt = 0; kt < 4; ++kt)
            A2[ht][kt] = *(const f16x8*)(w2p + ((size_t)(kt * 8 + wv * 2 + ht) * 64 + l) * 8);

    // ---- epilogue1: +b1, relu -> sT (aliases sA) ----
    f16* sT = sA;
#pragma unroll
    for (int ht = 0; ht < 2; ++ht) {
        const int hidb = 32 * wv + 16 * ht + 4 * q;
        const float4 bb = *(const float4*)(b1 + hidb);
#pragma unroll
        for (int et = 0; et < 8; ++et) {
            const f32x4 v = acc[ht][et];
            float x0 = fmaxf(v[0] + bb.x, 0.f), x1 = fmaxf(v[1] + bb.y, 0.f);
            float x2 = fmaxf(v[2] + bb.z, 0.f), x3 = fmaxf(v[3] + bb.w, 0.f);
            f16x4 o; o[0] = (f16)x0; o[1] = (f16)x1; o[2] = (f16)x2; o[3] = (f16)x3;
            *(f16x4*)(sT + (16 * et + li) * PAD_T + hidb) = o;
        }
    }
    __syncthreads();                                  // S3: sT ready

    // ---- GEMM2: K=128 ----
    f32x4 acc2[2][8];
#pragma unroll
    for (int i = 0; i < 2; ++i)
#pragma unroll
        for (int j = 0; j < 8; ++j) acc2[i][j] = (f32x4){0.f, 0.f, 0.f, 0.f};
#pragma unroll
    for (int kt = 0; kt < 4; ++kt) {
#pragma unroll
        for (int et = 0; et < 8; ++et) {
            const f16x8 b = *(const f16x8*)(sT + (16 * et + li) * PAD_T + 32 * kt + 8 * q);
            acc2[0][et] = mfma16(A2[0][kt], b, acc2[0][et]);
            acc2[1][et] = mfma16(A2[1][kt], b, acc2[1][et]);
        }
    }
    __syncthreads();                                  // S4: sT reads done

    // ---- epilogue2: x = upd + b2 + h -> sX f32 (aliases sA) ----
    float* sX = (float*)sA;            // stride 132 f32
#pragma unroll
    for (int ht = 0; ht < 2; ++ht) {
        const int hidb = 32 * wv + 16 * ht + 4 * q;
        const float4 bb = *(const float4*)(b2 + hidb);
#pragma unroll
        for (int et = 0; et < 8; ++et) {
            const int node = 16 * et + li;
            const int nc   = min(nbase + node, N - 1);
            const float4 hv = *(const float4*)(h + (size_t)nc * HD + hidb);
            const f32x4 v = acc2[ht][et];
            f32x4 x;
            x[0] = v[0] + bb.x + hv.x;
            x[1] = v[1] + bb.y + hv.y;
            x[2] = v[2] + bb.z + hv.z;
            x[3] = v[3] + bb.w + hv.w;
            *(f32x4*)(sX + (size_t)node * 132 + hidb) = x;
        }
    }
    __syncthreads();                                  // S5

    // ---- LayerNorm ----
    {
        const int node  = t >> 1;
        const int half2 = t & 1;
        const float* px = sX + node * 132 + half2 * 64;
        float s = 0.f, sq = 0.f;
#pragma unroll
        for (int i = 0; i < 16; ++i) {
            const float4 v = *(const float4*)(px + i * 4);
            s  += v.x + v.y + v.z + v.w;
            sq += v.x * v.x + v.y * v.y + v.z * v.z + v.w * v.w;
        }
        s  += __shfl_xor(s, 1);
        sq += __shfl_xor(sq, 1);
        if (!half2) {
            const float mean = s * (1.f / HD);
            const float var  = sq * (1.f / HD) - mean * mean;
            sMV[node]       = mean;
            sMV[BMN + node] = rsqrtf(var + 1e-5f);
        }
    }
    __syncthreads();                                  // S6

#pragma unroll
    for (int i = 0; i < 16; ++i) {
        const int idx  = t + i * 256;
        const int node = idx >> 5;
        const int c4   = (idx & 31) * 4;
        if (nbase + node < N) {
            const float4 xv = *(const float4*)(sX + node * 132 + c4);
            const float4 g4 = *(const float4*)(gamma + c4);
            const float4 b4 = *(const float4*)(beta + c4);
            const float mean = sMV[node];
            const float rstd = sMV[BMN + node];
            float4 o;
            o.x = (xv.x - mean) * rstd * g4.x + b4.x;
            o.y = (xv.y - mean) * rstd * g4.y + b4.y;
            o.z = (xv.z - mean) * rstd * g4.z + b4.z;
            o.w = (xv.w - mean) * rstd * g4.w + b4.w;
            *(float4*)(out + (size_t)(nbase + node) * HD + c4) = o;
        }
    }
}

// ---------------------------------------------------------------- launch
extern "C" void kernel_launch(void* const* d_in, const int* in_sizes, int n_in,
                              void* d_out, int out_size, void* d_ws, size_t ws_size,
                              hipStream_t stream)
{
    const float* h     = (const float*)d_in[0];
    const int*   eidx  = (const int*)  d_in[1];
    const float* ea    = (const float*)d_in[2];
    const float* ew1   = (const float*)d_in[3];
    const float* eb1   = (const float*)d_in[4];
    const float* ew2   = (const float*)d_in[5];
    const float* eb2   = (const float*)d_in[6];
    const float* nw1   = (const float*)d_in[7];
    const float* nb1   = (const float*)d_in[8];
    const float* nw2   = (const float*)d_in[9];
    const float* nb2   = (const float*)d_in[10];
    const float* gamma = (const float*)d_in[11];
    const float* beta  = (const float*)d_in[12];
    float* out = (float*)d_out;

    const int N = in_sizes[0] / HD;
    const int E = in_sizes[1] / 2;
    const int ntiles = (E + BME - 1) / BME;
    const int nb = (N + 1023) / 1024;

    size_t off = 0;
    auto alloc = [&](size_t bytes) {
        size_t o = off; off += (bytes + 255) & ~(size_t)255; return o;
    };
    const size_t o_agg  = alloc((size_t)N * HD * sizeof(float));
    const size_t o_h16  = alloc((size_t)N * HD * sizeof(f16));
    const size_t o_bnd  = alloc((size_t)2 * ntiles * HD * sizeof(float));
    const size_t o_bid  = alloc((size_t)2 * ntiles * sizeof(int));
    const size_t o_rank = alloc((size_t)E * sizeof(int));
    const size_t o_es   = alloc((size_t)E * sizeof(int));
    const size_t o_ed   = alloc((size_t)E * sizeof(int));
    const size_t o_ee   = alloc((size_t)E * sizeof(int));
    const size_t o_rs   = alloc((size_t)(N + 1) * sizeof(int));
    const size_t o_cnt  = alloc((size_t)N * sizeof(int));
    const size_t o_bs   = alloc((size_t)(nb + 1) * sizeof(int));
    const size_t o_bo   = alloc((size_t)(nb + 1) * sizeof(int));
    const size_t o_w1p  = alloc((size_t)9 * 8 * 64 * 8 * sizeof(f16));
    const size_t o_w2p  = alloc((size_t)4 * 8 * 64 * 8 * sizeof(f16));
    const size_t o_n1p  = alloc((size_t)8 * 8 * 64 * 8 * sizeof(f16));
    const size_t o_n2p  = alloc((size_t)4 * 8 * 64 * 8 * sizeof(f16));
    const bool csr = (off <= ws_size) && (nb <= 256);
    char* ws = (char*)d_ws;

    float* agg = (float*)(ws + o_agg);
    f16*   h16 = (f16*)(ws + o_h16);
    f16*   w1p = (f16*)(ws + o_w1p);
    f16*   w2p = (f16*)(ws + o_w2p);
    f16*   n1p = (f16*)(ws + o_n1p);
    f16*   n2p = (f16*)(ws + o_n2p);

    if (csr) {
        float* bnd  = (float*)(ws + o_bnd);
        int* bndid  = (int*)(ws + o_bid);
        int* rank   = (int*)(ws + o_rank);
        int* esrc   = (int*)(ws + o_es);
        int* edst   = (int*)(ws + o_ed);
        int* eea    = (int*)(ws + o_ee);
        int* rs     = (int*)(ws + o_rs);
        int* cnt    = (int*)(ws + o_cnt);
        int* bsum   = (int*)(ws + o_bs);
        int* boff   = (int*)(ws + o_bo);

        zero_f32<<<1024, 256, 0, stream>>>((float4*)agg, (long)N * HD / 4);
        zero_i32<<<(N + 255) / 256, 256, 0, stream>>>(cnt, N);
        hist_kernel<<<(E + 255) / 256, 256, 0, stream>>>(eidx, rank, cnt, E);
        scan1_kernel<<<nb, 256, 0, stream>>>(cnt, bsum, N);
        scan2_kernel<<<1, 256, 0, stream>>>(bsum, boff, rs, nb, N);
        scan3_kernel<<<nb, 256, 0, stream>>>(cnt, boff, rs, N);
        pos_kernel<<<(E + 255) / 256, 256, 0, stream>>>(eidx, rs, rank, esrc, edst, eea, E);
        cvt_f16_kernel<<<2048, 256, 0, stream>>>(h, h16, (long)N * HD / 8);
        pack_all_kernel<<<50, 256, 0, stream>>>(ew1, ew2, nw1, nw2, w1p, w2p, n1p, n2p);
        edge_kernel<1><<<EGRID, 256, 0, stream>>>(
            h16, eidx, ea, w1p, eb1, w2p, eb2, agg, bnd, bndid,
            esrc, edst, eea, E, ntiles);
        fixup_kernel<<<(2 * ntiles + 3) / 4, 256, 0, stream>>>(bnd, bndid, agg, 2 * ntiles);
        node_kernel<<<(N + BMN - 1) / BMN, 256, 0, stream>>>(
            h16, h, agg, n1p, nb1, n2p, nb2, gamma, beta, out, N);
    } else {
        // fallback: dense f32 atomic aggregation (natural edge order)
        zero_f32<<<1024, 256, 0, stream>>>((float4*)agg, (long)N * HD / 4);
        cvt_f16_kernel<<<2048, 256, 0, stream>>>(h, h16, (long)N * HD / 8);
        pack_all_kernel<<<50, 256, 0, stream>>>(ew1, ew2, nw1, nw2, w1p, w2p, n1p, n2p);
        edge_kernel<0><<<EGRID, 256, 0, stream>>>(
            h16, eidx, ea, w1p, eb1, w2p, eb2, agg, nullptr, nullptr,
            nullptr, nullptr, nullptr, E, ntiles);
        node_kernel<<<(N + BMN - 1) / BMN, 256, 0, stream>>>(
            h16, h, agg, n1p, nb1, n2p, nb2, gamma, beta, out, N);
    }
}

// Round 18
// 265.181 us; speedup vs baseline: 1.5194x; 1.5194x over previous
//
#include <hip/hip_runtime.h>
#include <cstdint>

#define HD 128
#define ED 32
#define BME 32            // edges per tile (edge kernel)
#define BMN 128           // nodes per block (node kernel)
#define PAD_N 264         // node sA row stride f16: 256+8
#define PAD_T 136         // node sT row stride f16: 128+8
#define EGRID 512         // persistent edge blocks (2 per CU)

typedef _Float16 f16;
typedef __attribute__((ext_vector_type(2))) _Float16 f16x2;
typedef __attribute__((ext_vector_type(4))) _Float16 f16x4;
typedef __attribute__((ext_vector_type(8))) _Float16 f16x8;
typedef __attribute__((ext_vector_type(4))) float    f32x4;
typedef __attribute__((ext_vector_type(4))) unsigned int u32x4;

__device__ __forceinline__ f32x4 mfma16(f16x8 a, f16x8 b, f32x4 c) {
    return __builtin_amdgcn_mfma_f32_16x16x32_f16(a, b, c, 0, 0, 0);
}
__device__ __forceinline__ f16x8 cvt8(const float* p) {
    const float4 a0 = *(const float4*)p;
    const float4 a1 = *(const float4*)(p + 4);
    f16x8 v;
    v[0] = (f16)a0.x; v[1] = (f16)a0.y; v[2] = (f16)a0.z; v[3] = (f16)a0.w;
    v[4] = (f16)a1.x; v[5] = (f16)a1.y; v[6] = (f16)a1.z; v[7] = (f16)a1.w;
    return v;
}
// barrier that drains LDS only — vmem loads/stores stay in flight (T4)
__device__ __forceinline__ void barrier_lds() {
    asm volatile("s_waitcnt lgkmcnt(0)" ::: "memory");
    __builtin_amdgcn_s_barrier();
    __builtin_amdgcn_sched_barrier(0);
}

// ---------------------------------------------------------------- utility
__global__ __launch_bounds__(256) void zero_f32(float4* p, long n4) {
    long i = (long)blockIdx.x * blockDim.x + threadIdx.x;
    const long stride = (long)gridDim.x * blockDim.x;
    const float4 z = make_float4(0.f, 0.f, 0.f, 0.f);
    for (; i < n4; i += stride) p[i] = z;
}
__global__ __launch_bounds__(256) void zero_i32(int* p, int n) {
    int i = blockIdx.x * blockDim.x + threadIdx.x;
    if (i < n) p[i] = 0;
}
__global__ __launch_bounds__(256)
void cvt_f16_kernel(const float* __restrict__ x, f16* __restrict__ y, long n8) {
    long i = blockIdx.x * 256 + threadIdx.x;
    const long stride = (long)gridDim.x * 256;
    for (; i < n8; i += stride) *(f16x8*)(y + i * 8) = cvt8(x + i * 8);
}
// pack all 4 weight mats -> frag order [kt][wi][lane][8] f16  (wi = hid16 slice)
__global__ __launch_bounds__(256)
void pack_all_kernel(const float* __restrict__ ew1, const float* __restrict__ ew2,
                     const float* __restrict__ nw1, const float* __restrict__ nw2,
                     f16* __restrict__ w1p, f16* __restrict__ w2p,
                     f16* __restrict__ n1p, f16* __restrict__ n2p)
{
    const int b = blockIdx.x;
    const float* w; f16* wp; int base;
    if (b < 18)      { w = ew1; wp = w1p; base = b; }
    else if (b < 26) { w = ew2; wp = w2p; base = b - 18; }
    else if (b < 42) { w = nw1; wp = n1p; base = b - 26; }
    else             { w = nw2; wp = n2p; base = b - 42; }
    const int idx = base * 256 + threadIdx.x;
    const int l  = idx & 63;
    const int fr = idx >> 6;
    const int wi = fr & 7, kt = fr >> 3;
    const int lii = l & 15, qq = l >> 4;
    const float* p = w + (size_t)(32 * kt + 8 * qq) * HD + 16 * wi + lii;
    f16x8 v;
#pragma unroll
    for (int e2 = 0; e2 < 8; ++e2) v[e2] = (f16)p[(size_t)e2 * HD];
    *(f16x8*)(wp + (size_t)idx * 8) = v;
}

// ---------------------------------------------------------------- CSR build
__global__ __launch_bounds__(256)
void hist_kernel(const int* __restrict__ eidx, int* __restrict__ rank,
                 int* __restrict__ cnt, int E) {
    int e = blockIdx.x * 256 + threadIdx.x;
    if (e < E) rank[e] = atomicAdd(&cnt[eidx[E + e]], 1);
}
__global__ __launch_bounds__(1024)
void scan_kernel(const int* __restrict__ cnt, int* __restrict__ rs, int N) {
    __shared__ int wsum[16];
    __shared__ int s_carry;
    const int t = threadIdx.x, lane = t & 63, wid = t >> 6;
    if (t == 0) s_carry = 0;
    __syncthreads();
    for (int base = 0; base < N; base += 1024) {
        const int i = base + t;
        const int v = (i < N) ? cnt[i] : 0;
        int incl = v;
#pragma unroll
        for (int off = 1; off < 64; off <<= 1) {
            int u = __shfl_up(incl, off, 64);
            if (lane >= off) incl += u;
        }
        if (lane == 63) wsum[wid] = incl;
        __syncthreads();
        if (t == 0) {
            int s = 0;
#pragma unroll
            for (int w = 0; w < 16; ++w) { int x = wsum[w]; wsum[w] = s; s += x; }
        }
        __syncthreads();
        const int carry = s_carry;
        if (i < N) rs[i] = carry + wsum[wid] + incl - v;
        __syncthreads();
        if (t == 1023) s_carry = carry + wsum[15] + incl;
        __syncthreads();
    }
    if (threadIdx.x == 0) rs[N] = s_carry;
}
__global__ __launch_bounds__(256)
void pos_kernel(const int* __restrict__ eidx, const int* __restrict__ rs,
                int* __restrict__ pos, int E) {
    int e = blockIdx.x * 256 + threadIdx.x;
    if (e < E) pos[e] = rs[eidx[E + e]] + pos[e];
}

// ---------------------------------------------------------------- edges
// 256 threads, 4 waves; wave w owns hid slice [32w,32w+32) (2 A-frags/kt) and
// ALL 32 edges -> each B ds_read feeds 2 MFMAs (2:1). Weights resident
// (VGPR=112). MODE 0: atomic scatter. MODE 1: f16 row store at m[pos[e]].
template <int MODE>
__global__ __launch_bounds__(256, 2)
void edge_kernel(const f16*   __restrict__ h16,
                 const int*   __restrict__ eidx,
                 const float* __restrict__ ea,
                 const f16*   __restrict__ w1p,   // packed frags, KT=9
                 const float* __restrict__ b1,
                 const f16*   __restrict__ w2p,   // packed frags, KT=4
                 const float* __restrict__ b2,
                 void*        __restrict__ aggm,  // MODE0: float* ; MODE1: f16*
                 const int*   __restrict__ pos,
                 int E, int ntiles)
{
    __shared__ __align__(16) f16 sA[BME * 320];   // 20480 B (40 chunks/row, 36 used)
    __shared__ __align__(16) f16 sT[BME * 128];   // 8192 B  (16 chunks/row)
    __shared__ int sIdx[2][BME];

    const int t  = threadIdx.x;
    const int l  = t & 63;
    const int wv = t >> 6;            // 0..3  (hid slice [32wv, 32wv+32))
    const int li = l & 15;
    const int q  = l >> 4;            // 0..3
    const int lm = l & 7;             // row&7 for rows 16*e+li
    const int r  = t >> 3;            // staging row 0..31
    const int q8 = t & 7;             // staging chunk id within row

    // ---- weights -> registers, once per block (104 VGPR, resident) ----
    f16x8 A1[2][9], A2[2][4];
#pragma unroll
    for (int ht = 0; ht < 2; ++ht) {
#pragma unroll
        for (int kt = 0; kt < 9; ++kt)
            A1[ht][kt] = *(const f16x8*)(w1p + ((size_t)(kt * 8 + wv * 2 + ht) * 64 + l) * 8);
#pragma unroll
        for (int kt = 0; kt < 4; ++kt)
            A2[ht][kt] = *(const f16x8*)(w2p + ((size_t)(kt * 8 + wv * 2 + ht) * 64 + l) * 8);
    }

    // ---- prefetch: tile row-data -> registers ----
    f16x8 d[4];
    f16x8 d4;                          // ea chunk (q8<4 only)
    int   psr = 0;
    auto prefetch = [&](int tile) {
        const int ec  = min(tile * BME + r, E - 1);
        const int src = eidx[ec];
        const int dst = eidx[E + ec];
        psr = (MODE == 0) ? dst : pos[ec];
        const f16* hs = h16 + (size_t)src * HD;
        const f16* hd = h16 + (size_t)dst * HD;
#pragma unroll
        for (int i = 0; i < 4; ++i) {
            const int c = (q8 + 8 * i) * 8;        // < 256 always
            d[i] = (c < HD) ? *(const f16x8*)(hs + c)
                            : *(const f16x8*)(hd + (c - HD));
        }
        if (q8 < 4) d4 = cvt8(ea + (size_t)ec * ED + q8 * 8);
    };

    int tb = blockIdx.x;
    if (tb < ntiles) prefetch(tb);
    int par = 0;

    for (; tb < ntiles; tb += gridDim.x, par ^= 1) {
        // ---- stage regs -> sA (swizzled) ----
        {
            f16* row = sA + r * 320;
            const int sw = r & 7;
#pragma unroll
            for (int i = 0; i < 4; ++i) {
                const int ch = q8 + 8 * i;
                *(f16x8*)(row + ((ch ^ sw) * 8)) = d[i];
            }
            if (q8 < 4)
                *(f16x8*)(row + (((q8 + 32) ^ sw) * 8)) = d4;
            if (q8 == 0) sIdx[par][r] = psr;
        }
        barrier_lds();                                    // S1: sA ready

        const int nt = tb + (int)gridDim.x;
        if (nt < ntiles) prefetch(nt);                    // floats across barriers

        // ---- GEMM1: K=288; 1 ds_read feeds 2 MFMAs ----
        f32x4 acc[2][2];
#pragma unroll
        for (int i = 0; i < 2; ++i)
#pragma unroll
            for (int j = 0; j < 2; ++j) acc[i][j] = (f32x4){0.f, 0.f, 0.f, 0.f};
#pragma unroll
        for (int kt = 0; kt < 9; ++kt) {
#pragma unroll
            for (int e = 0; e < 2; ++e) {
                const f16x8 b = *(const f16x8*)(sA + (16 * e + li) * 320
                                                + (((4 * kt + q) ^ lm) * 8));
                acc[0][e] = mfma16(A1[0][kt], b, acc[0][e]);
                acc[1][e] = mfma16(A1[1][kt], b, acc[1][e]);
            }
        }

        // ---- epilogue1: +b1, relu -> sT (swizzled) ----
#pragma unroll
        for (int ht = 0; ht < 2; ++ht) {
            const int hidb = 32 * wv + 16 * ht + 4 * q;
            const float4 bb = *(const float4*)(b1 + hidb);
            const int chT = hidb >> 3;
            const int off = hidb & 7;                     // 0 or 4
#pragma unroll
            for (int e = 0; e < 2; ++e) {
                const f32x4 v = acc[ht][e];
                float x0 = fmaxf(v[0] + bb.x, 0.f), x1 = fmaxf(v[1] + bb.y, 0.f);
                float x2 = fmaxf(v[2] + bb.z, 0.f), x3 = fmaxf(v[3] + bb.w, 0.f);
                f16x4 o; o[0] = (f16)x0; o[1] = (f16)x1; o[2] = (f16)x2; o[3] = (f16)x3;
                *(f16x4*)(sT + (16 * e + li) * 128 + ((chT ^ lm) * 8) + off) = o;
            }
        }
        barrier_lds();                                    // S2: sT ready

        // ---- GEMM2: K=128 ----
        f32x4 acc2[2][2];
#pragma unroll
        for (int i = 0; i < 2; ++i)
#pragma unroll
            for (int j = 0; j < 2; ++j) acc2[i][j] = (f32x4){0.f, 0.f, 0.f, 0.f};
#pragma unroll
        for (int kt = 0; kt < 4; ++kt) {
#pragma unroll
            for (int e = 0; e < 2; ++e) {
                const f16x8 b = *(const f16x8*)(sT + (16 * e + li) * 128
                                                + (((4 * kt + q) ^ lm) * 8));
                acc2[0][e] = mfma16(A2[0][kt], b, acc2[0][e]);
                acc2[1][e] = mfma16(A2[1][kt], b, acc2[1][e]);
            }
        }

        if (MODE == 0) {
            float* agg = (float*)aggm;
#pragma unroll
            for (int ht = 0; ht < 2; ++ht) {
                const int hidb = 32 * wv + 16 * ht + 4 * q;
                const float4 bb = *(const float4*)(b2 + hidb);
#pragma unroll
                for (int e = 0; e < 2; ++e) {
                    const int edge = 16 * e + li;
                    if (tb * BME + edge < E) {
                        float* p = agg + (size_t)sIdx[par][edge] * HD + hidb;
                        const f32x4 v = acc2[ht][e];
                        atomicAdd(p + 0, v[0] + bb.x);
                        atomicAdd(p + 1, v[1] + bb.y);
                        atomicAdd(p + 2, v[2] + bb.z);
                        atomicAdd(p + 3, v[3] + bb.w);
                    }
                }
            }
            barrier_lds();
        } else {
            barrier_lds();                                // S3: GEMM2 done reading sT
#pragma unroll
            for (int ht = 0; ht < 2; ++ht) {
                const int hidb = 32 * wv + 16 * ht + 4 * q;
                const float4 bb = *(const float4*)(b2 + hidb);
                const int chT = hidb >> 3;
                const int off = hidb & 7;
#pragma unroll
                for (int e = 0; e < 2; ++e) {
                    const f32x4 v = acc2[ht][e];
                    f16x4 o;
                    o[0] = (f16)(v[0] + bb.x); o[1] = (f16)(v[1] + bb.y);
                    o[2] = (f16)(v[2] + bb.z); o[3] = (f16)(v[3] + bb.w);
                    *(f16x4*)(sT + (16 * e + li) * 128 + ((chT ^ lm) * 8) + off) = o;
                }
            }
            barrier_lds();                                // S4: result tile ready
            f16* m = (f16*)aggm;
#pragma unroll
            for (int i = 0; i < 2; ++i) {
                const int idx  = t + i * 256;             // 0..511
                const int row2 = idx >> 4;                // 0..31
                const int c    = idx & 15;
                if (tb * BME + row2 < E) {
                    const f16x8 v = *(const f16x8*)(sT + row2 * 128
                                                    + ((c ^ (row2 & 7)) * 8));
                    __builtin_nontemporal_store(*(const u32x4*)&v,
                        (u32x4*)(m + (size_t)sIdx[par][row2] * HD + c * 8));
                }
            }
        }
    }
}

// ---------------------------------------------------------------- nodes
// Gather fused into staging: node n's CSR segment of m is contiguous.
// CSR=1: agg = sum m[rs[n]..rs[n+1]).  CSR=0: agg from dense f32 aggf.
template <int CSR>
__global__ __launch_bounds__(256, 2)
void node_kernel(const f16*   __restrict__ h16,
                 const float* __restrict__ h,      // f32 residual
                 const f16*   __restrict__ m,
                 const int*   __restrict__ rs,
                 const float* __restrict__ aggf,
                 const f16*   __restrict__ w1p,    // KT=8
                 const float* __restrict__ b1,
                 const f16*   __restrict__ w2p,    // KT=4
                 const float* __restrict__ b2,
                 const float* __restrict__ gamma,
                 const float* __restrict__ beta,
                 float*       __restrict__ out,
                 int N)
{
    __shared__ __align__(16) f16 sA[BMN * PAD_N];  // 67584 B; sT & sX alias
    __shared__ float sMV[2 * BMN];

    const int t  = threadIdx.x;
    const int l  = t & 63;
    const int wv = t >> 6;
    const int li = l & 15;
    const int q  = l >> 4;
    const int nbase = blockIdx.x * BMN;

    // ---- stage sA[node][0..256) = [h16 | agg-sum] : 2 threads/node ----
    {
        const int r = t >> 1, half = t & 1;
        const int node = min(nbase + r, N - 1);
        f16* rowp = sA + r * PAD_N;
        {
            const f16* srcp = h16 + (size_t)node * HD + half * 64;
#pragma unroll
            for (int i = 0; i < 8; ++i)
                *(f16x8*)(rowp + half * 64 + i * 8) = *(const f16x8*)(srcp + i * 8);
        }
        if (CSR) {
            const int s = rs[node], en = rs[node + 1];
            float ag[64];
#pragma unroll
            for (int i = 0; i < 64; ++i) ag[i] = 0.f;
            const f16* base = m + (size_t)s * HD + half * 64;
            for (int j = 0; j < en - s; ++j) {
                const f16* rp = base + (size_t)j * HD;
#pragma unroll
                for (int i = 0; i < 8; ++i) {
                    const f16x8 v = *(const f16x8*)(rp + i * 8);
#pragma unroll
                    for (int k2 = 0; k2 < 8; ++k2) ag[i * 8 + k2] += (float)v[k2];
                }
            }
#pragma unroll
            for (int i = 0; i < 8; ++i) {
                f16x8 o;
#pragma unroll
                for (int k2 = 0; k2 < 8; ++k2) o[k2] = (f16)ag[i * 8 + k2];
                *(f16x8*)(rowp + 128 + half * 64 + i * 8) = o;
            }
        } else {
            const float* srcp = aggf + (size_t)node * HD + half * 64;
#pragma unroll
            for (int i = 0; i < 8; ++i)
                *(f16x8*)(rowp + 128 + half * 64 + i * 8) = cvt8(srcp + i * 8);
        }
    }
    __syncthreads();                                  // S1

    // ---- A1 -> registers ----
    f16x8 A1[2][8];
#pragma unroll
    for (int ht = 0; ht < 2; ++ht)
#pragma unroll
        for (int kt = 0; kt < 8; ++kt)
            A1[ht][kt] = *(const f16x8*)(w1p + ((size_t)(kt * 8 + wv * 2 + ht) * 64 + l) * 8);

    // ---- GEMM1: K=256 ----
    f32x4 acc[2][8];
#pragma unroll
    for (int i = 0; i < 2; ++i)
#pragma unroll
        for (int j = 0; j < 8; ++j) acc[i][j] = (f32x4){0.f, 0.f, 0.f, 0.f};
#pragma unroll
    for (int kt = 0; kt < 8; ++kt) {
#pragma unroll
        for (int et = 0; et < 8; ++et) {
            const f16x8 b = *(const f16x8*)(sA + (16 * et + li) * PAD_N + 32 * kt + 8 * q);
            acc[0][et] = mfma16(A1[0][kt], b, acc[0][et]);
            acc[1][et] = mfma16(A1[1][kt], b, acc[1][et]);
        }
    }
    __syncthreads();                                  // S2: sA reads done (alias!)

    // ---- A2 -> registers ----
    f16x8 A2[2][4];
#pragma unroll
    for (int ht = 0; ht < 2; ++ht)
#pragma unroll
        for (int kt = 0; kt < 4; ++kt)
            A2[ht][kt] = *(const f16x8*)(w2p + ((size_t)(kt * 8 + wv * 2 + ht) * 64 + l) * 8);

    // ---- epilogue1: +b1, relu -> sT (aliases sA) ----
    f16* sT = sA;
#pragma unroll
    for (int ht = 0; ht < 2; ++ht) {
        const int hidb = 32 * wv + 16 * ht + 4 * q;
        const float4 bb = *(const float4*)(b1 + hidb);
#pragma unroll
        for (int et = 0; et < 8; ++et) {
            const f32x4 v = acc[ht][et];
            float x0 = fmaxf(v[0] + bb.x, 0.f), x1 = fmaxf(v[1] + bb.y, 0.f);
            float x2 = fmaxf(v[2] + bb.z, 0.f), x3 = fmaxf(v[3] + bb.w, 0.f);
            f16x4 o; o[0] = (f16)x0; o[1] = (f16)x1; o[2] = (f16)x2; o[3] = (f16)x3;
            *(f16x4*)(sT + (16 * et + li) * PAD_T + hidb) = o;
        }
    }
    __syncthreads();                                  // S3: sT ready

    // ---- GEMM2: K=128 ----
    f32x4 acc2[2][8];
#pragma unroll
    for (int i = 0; i < 2; ++i)
#pragma unroll
        for (int j = 0; j < 8; ++j) acc2[i][j] = (f32x4){0.f, 0.f, 0.f, 0.f};
#pragma unroll
    for (int kt = 0; kt < 4; ++kt) {
#pragma unroll
        for (int et = 0; et < 8; ++et) {
            const f16x8 b = *(const f16x8*)(sT + (16 * et + li) * PAD_T + 32 * kt + 8 * q);
            acc2[0][et] = mfma16(A2[0][kt], b, acc2[0][et]);
            acc2[1][et] = mfma16(A2[1][kt], b, acc2[1][et]);
        }
    }
    __syncthreads();                                  // S4: sT reads done

    // ---- epilogue2: x = upd + b2 + h -> sX f32 (aliases sA) ----
    float* sX = (float*)sA;            // stride 132 f32
#pragma unroll
    for (int ht = 0; ht < 2; ++ht) {
        const int hidb = 32 * wv + 16 * ht + 4 * q;
        const float4 bb = *(const float4*)(b2 + hidb);
#pragma unroll
        for (int et = 0; et < 8; ++et) {
            const int node = 16 * et + li;
            const int nc   = min(nbase + node, N - 1);
            const float4 hv = *(const float4*)(h + (size_t)nc * HD + hidb);
            const f32x4 v = acc2[ht][et];
            f32x4 x;
            x[0] = v[0] + bb.x + hv.x;
            x[1] = v[1] + bb.y + hv.y;
            x[2] = v[2] + bb.z + hv.z;
            x[3] = v[3] + bb.w + hv.w;
            *(f32x4*)(sX + (size_t)node * 132 + hidb) = x;
        }
    }
    __syncthreads();                                  // S5

    // ---- LayerNorm ----
    {
        const int node  = t >> 1;
        const int half2 = t & 1;
        const float* px = sX + node * 132 + half2 * 64;
        float s = 0.f, sq = 0.f;
#pragma unroll
        for (int i = 0; i < 16; ++i) {
            const float4 v = *(const float4*)(px + i * 4);
            s  += v.x + v.y + v.z + v.w;
            sq += v.x * v.x + v.y * v.y + v.z * v.z + v.w * v.w;
        }
        s  += __shfl_xor(s, 1);
        sq += __shfl_xor(sq, 1);
        if (!half2) {
            const float mean = s * (1.f / HD);
            const float var  = sq * (1.f / HD) - mean * mean;
            sMV[node]       = mean;
            sMV[BMN + node] = rsqrtf(var + 1e-5f);
        }
    }
    __syncthreads();                                  // S6

#pragma unroll
    for (int i = 0; i < 16; ++i) {
        const int idx  = t + i * 256;
        const int node = idx >> 5;
        const int c4   = (idx & 31) * 4;
        if (nbase + node < N) {
            const float4 xv = *(const float4*)(sX + node * 132 + c4);
            const float4 g4 = *(const float4*)(gamma + c4);
            const float4 b4 = *(const float4*)(beta + c4);
            const float mean = sMV[node];
            const float rstd = sMV[BMN + node];
            float4 o;
            o.x = (xv.x - mean) * rstd * g4.x + b4.x;
            o.y = (xv.y - mean) * rstd * g4.y + b4.y;
            o.z = (xv.z - mean) * rstd * g4.z + b4.z;
            o.w = (xv.w - mean) * rstd * g4.w + b4.w;
            *(float4*)(out + (size_t)(nbase + node) * HD + c4) = o;
        }
    }
}

// ---------------------------------------------------------------- launch
extern "C" void kernel_launch(void* const* d_in, const int* in_sizes, int n_in,
                              void* d_out, int out_size, void* d_ws, size_t ws_size,
                              hipStream_t stream)
{
    const float* h     = (const float*)d_in[0];
    const int*   eidx  = (const int*)  d_in[1];
    const float* ea    = (const float*)d_in[2];
    const float* ew1   = (const float*)d_in[3];
    const float* eb1   = (const float*)d_in[4];
    const float* ew2   = (const float*)d_in[5];
    const float* eb2   = (const float*)d_in[6];
    const float* nw1   = (const float*)d_in[7];
    const float* nb1   = (const float*)d_in[8];
    const float* nw2   = (const float*)d_in[9];
    const float* nb2   = (const float*)d_in[10];
    const float* gamma = (const float*)d_in[11];
    const float* beta  = (const float*)d_in[12];
    float* out = (float*)d_out;

    const int N = in_sizes[0] / HD;
    const int E = in_sizes[1] / 2;
    const int ntiles = (E + BME - 1) / BME;

    size_t off = 0;
    auto alloc = [&](size_t bytes) {
        size_t o = off; off += (bytes + 255) & ~(size_t)255; return o;
    };
    const size_t o_m    = alloc((size_t)E * HD * sizeof(f16));
    const size_t o_h16  = alloc((size_t)N * HD * sizeof(f16));
    const size_t o_pos  = alloc((size_t)E * sizeof(int));
    const size_t o_rs   = alloc((size_t)(N + 1) * sizeof(int));
    const size_t o_cnt  = alloc((size_t)N * sizeof(int));
    const size_t o_w1p  = alloc((size_t)9 * 8 * 64 * 8 * sizeof(f16));
    const size_t o_w2p  = alloc((size_t)4 * 8 * 64 * 8 * sizeof(f16));
    const size_t o_n1p  = alloc((size_t)8 * 8 * 64 * 8 * sizeof(f16));
    const size_t o_n2p  = alloc((size_t)4 * 8 * 64 * 8 * sizeof(f16));
    const bool csr = (off <= ws_size);
    char* ws = (char*)d_ws;

    if (csr) {
        f16* mb   = (f16*)(ws + o_m);
        f16* h16  = (f16*)(ws + o_h16);
        int* pos  = (int*)(ws + o_pos);
        int* rs   = (int*)(ws + o_rs);
        int* cnt  = (int*)(ws + o_cnt);
        f16* w1p  = (f16*)(ws + o_w1p);
        f16* w2p  = (f16*)(ws + o_w2p);
        f16* n1p  = (f16*)(ws + o_n1p);
        f16* n2p  = (f16*)(ws + o_n2p);

        zero_i32<<<(N + 255) / 256, 256, 0, stream>>>(cnt, N);
        hist_kernel<<<(E + 255) / 256, 256, 0, stream>>>(eidx, pos, cnt, E);
        scan_kernel<<<1, 1024, 0, stream>>>(cnt, rs, N);
        pos_kernel<<<(E + 255) / 256, 256, 0, stream>>>(eidx, rs, pos, E);
        cvt_f16_kernel<<<2048, 256, 0, stream>>>(h, h16, (long)N * HD / 8);
        pack_all_kernel<<<50, 256, 0, stream>>>(ew1, ew2, nw1, nw2, w1p, w2p, n1p, n2p);
        edge_kernel<1><<<EGRID, 256, 0, stream>>>(
            h16, eidx, ea, w1p, eb1, w2p, eb2, (void*)mb, pos, E, ntiles);
        node_kernel<1><<<(N + BMN - 1) / BMN, 256, 0, stream>>>(
            h16, h, mb, rs, nullptr, n1p, nb1, n2p, nb2, gamma, beta, out, N);
    } else {
        // fallback: dense f32 atomic aggregation
        size_t foff = 0;
        auto falloc = [&](size_t bytes) {
            size_t o = foff; foff += (bytes + 255) & ~(size_t)255; return o;
        };
        float* agg = (float*)(ws + falloc((size_t)N * HD * sizeof(float)));
        f16*   h16 = (f16*)  (ws + falloc((size_t)N * HD * sizeof(f16)));
        f16*   w1p = (f16*)  (ws + falloc((size_t)9 * 8 * 64 * 8 * sizeof(f16)));
        f16*   w2p = (f16*)  (ws + falloc((size_t)4 * 8 * 64 * 8 * sizeof(f16)));
        f16*   n1p = (f16*)  (ws + falloc((size_t)8 * 8 * 64 * 8 * sizeof(f16)));
        f16*   n2p = (f16*)  (ws + falloc((size_t)4 * 8 * 64 * 8 * sizeof(f16)));

        zero_f32<<<1024, 256, 0, stream>>>((float4*)agg, (long)N * HD / 4);
        cvt_f16_kernel<<<2048, 256, 0, stream>>>(h, h16, (long)N * HD / 8);
        pack_all_kernel<<<50, 256, 0, stream>>>(ew1, ew2, nw1, nw2, w1p, w2p, n1p, n2p);
        edge_kernel<0><<<EGRID, 256, 0, stream>>>(
            h16, eidx, ea, w1p, eb1, w2p, eb2, (void*)agg, nullptr, E, ntiles);
        node_kernel<0><<<(N + BMN - 1) / BMN, 256, 0, stream>>>(
            h16, h, nullptr, nullptr, agg, n1p, nb1, n2p, nb2, gamma, beta, out, N);
    }
}